// Round 1
// 789.708 us; speedup vs baseline: 4.4244x; 4.4244x over previous
//
#include <hip/hip_runtime.h>

typedef unsigned int u32;

// ---- workspace layout (float offsets) ----
#define WS_WSG   0        // 64x256: Wsrc @ Wgate
#define WS_WDG   16384    // 64x256: Wdst @ Wgate
#define WS_WEG   32768    // 8x256 : Wenc @ Wgate
#define WS_BALL  34816    // 256   : (benc+bsrc+bdst) @ Wgate + bgate
#define WS_GS    35072    // N x 256, then GD = WS_GS + N*256

// ---------------------------------------------------------------- zero out
__global__ void zero_k(float* p, int n) {
    int i = blockIdx.x * blockDim.x + threadIdx.x;
    int st = gridDim.x * blockDim.x;
    for (; i < n; i += st) p[i] = 0.0f;
}

// ---------------------------------------------------------------- compose weights
// 73 blocks x 256 threads. Rows 0..63: WsG & WdG; 64..71: WeG; 72: bias row.
__global__ void compose_k(const float* __restrict__ Wsrc, const float* __restrict__ Wdst,
                          const float* __restrict__ Wenc, const float* __restrict__ benc,
                          const float* __restrict__ bsrc, const float* __restrict__ bdst,
                          const float* __restrict__ Wgate, const float* __restrict__ bgate,
                          float* __restrict__ ws) {
    const int j = threadIdx.x;           // 0..255
    const int r = blockIdx.x;            // 0..72
    if (r < 64) {
        float a = 0.f, b = 0.f;
        for (int c = 0; c < 64; ++c) {
            const float wg = Wgate[c * 256 + j];
            a += Wsrc[r * 64 + c] * wg;
            b += Wdst[r * 64 + c] * wg;
        }
        ws[WS_WSG + r * 256 + j] = a;
        ws[WS_WDG + r * 256 + j] = b;
    } else if (r < 72) {
        const int m = r - 64;
        float a = 0.f;
        for (int c = 0; c < 64; ++c) a += Wenc[m * 64 + c] * Wgate[c * 256 + j];
        ws[WS_WEG + m * 256 + j] = a;
    } else {
        float a = bgate[j];
        for (int c = 0; c < 64; ++c)
            a += (benc[c] + bsrc[c] + bdst[c]) * Wgate[c * 256 + j];
        ws[WS_BALL + j] = a;
    }
}

// ---------------------------------------------------------------- node precompute
// GS[n][j] = sum_k emb[n][k] * WsG[k][j];  GD likewise. 512 threads:
// tid<256 -> GS cols, tid>=256 -> GD cols; 4 nodes per group.
__global__ __launch_bounds__(512, 1) void nodepre_k(
    const float* __restrict__ emb, const float* __restrict__ ws,
    float* __restrict__ GS, float* __restrict__ GD, int N) {
    __shared__ float sW[32768];   // 128 KB: WsG then WdG
    __shared__ float sE[256];     // 4 node rows
    for (int i = threadIdx.x; i < 32768; i += 512) sW[i] = ws[i];
    __syncthreads();
    const int half = threadIdx.x >> 8;
    const int j = threadIdx.x & 255;
    const float* W = &sW[half * 16384];
    float* G = half ? GD : GS;
    const int ngroups = (N + 3) >> 2;
    for (int grp = blockIdx.x; grp < ngroups; grp += gridDim.x) {
        const int n0 = grp * 4;
        if (threadIdx.x < 256) {
            const int nn = n0 + (threadIdx.x >> 6);
            sE[threadIdx.x] = (nn < N) ? emb[nn * 64 + (threadIdx.x & 63)] : 0.f;
        }
        __syncthreads();
        float a0 = 0.f, a1 = 0.f, a2 = 0.f, a3 = 0.f;
        #pragma unroll 8
        for (int k = 0; k < 64; ++k) {
            const float w = W[k * 256 + j];
            a0 += sE[k] * w;
            a1 += sE[64 + k] * w;
            a2 += sE[128 + k] * w;
            a3 += sE[192 + k] * w;
        }
        if (n0 < N)     G[(size_t)n0 * 256 + j] = a0;
        if (n0 + 1 < N) G[(size_t)(n0 + 1) * 256 + j] = a1;
        if (n0 + 2 < N) G[(size_t)(n0 + 2) * 256 + j] = a2;
        if (n0 + 3 < N) G[(size_t)(n0 + 3) * 256 + j] = a3;
        __syncthreads();
    }
}

// ---------------------------------------------------------------- edge kernel (fast)
// One wave per edge. No shuffles: gate comes from gathered GS/GD rows + tiny
// radial matvec from LDS. Scatter-adds RAW smsg/vm into d_out (Ws/Wv applied later).
__global__ __launch_bounds__(256, 8) void edge_fast_k(
    const int* __restrict__ src, const int* __restrict__ dst,
    const float* __restrict__ r_ij, const float* __restrict__ z0g,
    const float* __restrict__ z1g, const float* __restrict__ GS,
    const float* __restrict__ GD, const float* __restrict__ WeG,
    const float* __restrict__ ball, float* __restrict__ out, int N, int E) {
    __shared__ float sWe[2048];   // 8 KB
    __shared__ float sBall[256];  // 1 KB
    __shared__ int sFl[2];

    if (threadIdx.x == 0) {
        const u32* ps = (const u32*)src;
        const u32* pd = (const u32*)dst;
        int s64 = 1, d64 = 1;
        for (int i = 1; i < 128; i += 2) {
            if (ps[i] != 0u) s64 = 0;
            if (pd[i] != 0u) d64 = 0;
        }
        sFl[0] = s64;
        sFl[1] = d64;
    }
    for (int i = threadIdx.x; i < 2048; i += 256) sWe[i] = WeG[i];
    if (threadIdx.x < 256) sBall[threadIdx.x] = ball[threadIdx.x];
    __syncthreads();

    const int wid = threadIdx.x >> 6, lane = threadIdx.x & 63;
    const int i64s = sFl[0], i64d = sFl[1];

    for (int e = blockIdx.x * 4 + wid; e < E; e += gridDim.x * 4) {
        const int s = i64s ? src[2 * e] : src[e];
        const int t = i64d ? dst[2 * e] : dst[e];
        if (s < 0 || s >= N || t < 0 || t >= N) continue;

        // issue all gathers up front
        const float* gs = GS + (size_t)s * 256 + lane;
        const float* gd = GD + (size_t)t * 256 + lane;
        const float a0 = gs[0], a1 = gs[64], a2 = gs[128], a3 = gs[192];
        const float b0 = gd[0], b1 = gd[64], b2 = gd[128], b3 = gd[192];
        const float z0v = z0g[t * 64 + lane];
        const float za = z1g[t * 192 + lane];
        const float zb = z1g[t * 192 + 64 + lane];
        const float zc = z1g[t * 192 + 128 + lane];
        const float r0 = r_ij[e * 3 + 0];
        const float r1 = r_ij[e * 3 + 1];
        const float r2 = r_ij[e * 3 + 2];

        float g0 = a0 + b0 + sBall[lane];
        float g1 = a1 + b1 + sBall[64 + lane];
        float g2 = a2 + b2 + sBall[128 + lane];
        float g3 = a3 + b3 + sBall[192 + lane];

        const float d = sqrtf(r0 * r0 + r1 * r1 + r2 * r2);
        #pragma unroll
        for (int m = 0; m < 8; ++m) {
            const float mu = 0.28571428571f * (float)m;   // linspace(0, 2, 8)
            const float tt = (d - mu) * 4.0f;             // / sigma, sigma = 0.25
            const float rm = __expf(-tt * tt);
            const float* w = &sWe[(m << 8) + lane];
            g0 += rm * w[0];
            g1 += rm * w[64];
            g2 += rm * w[128];
            g3 += rm * w[192];
        }

        // r_hat = v/sqrt(1+|v|^2), v = r_ij*3.5
        const float v0 = r0 * 3.5f, v1 = r1 * 3.5f, v2 = r2 * 3.5f;
        const float inv = rsqrtf(1.0f + v0 * v0 + v1 * v1 + v2 * v2);
        const float h0 = v0 * inv, h1 = v1 * inv, h2 = v2 * inv;

        const float uu = h0 * za + h1 * zb + h2 * zc;     // r_hat . z1_j

        const float smsg = g0 * z0v + g1 * uu;
        const float vm0 = g2 * za + g3 * h0 * z0v;
        const float vm1 = g2 * zb + g3 * h1 * z0v;
        const float vm2 = g2 * zc + g3 * h2 * z0v;

        atomicAdd(&out[s * 64 + lane], smsg);
        const int bo = N * 64 + s * 192 + lane;
        atomicAdd(&out[bo], vm0);
        atomicAdd(&out[bo + 64], vm1);
        atomicAdd(&out[bo + 128], vm2);
    }
}

// ---------------------------------------------------------------- node epilogue
// In place: out0[n] = S0[n] @ Ws ; out1[n][i] = V[n][i] @ Wv
__global__ __launch_bounds__(256) void nodepost_k(
    float* __restrict__ out, const float* __restrict__ Ws,
    const float* __restrict__ Wv, int N) {
    __shared__ float sWs[4096];
    __shared__ float sWv[4096];
    __shared__ float sRow[256];
    for (int i = threadIdx.x; i < 4096; i += 256) {
        sWs[i] = Ws[i];
        sWv[i] = Wv[i];
    }
    __syncthreads();
    const int j = threadIdx.x;
    const int part = j >> 6;       // 0: scalar, 1..3: vector components
    const int col = j & 63;
    const float* W = (part == 0) ? sWs : sWv;
    for (int n = blockIdx.x; n < N; n += gridDim.x) {
        const float v = (part == 0) ? out[n * 64 + j]
                                    : out[N * 64 + n * 192 + (j - 64)];
        sRow[j] = v;
        __syncthreads();
        const float* row = &sRow[part * 64];
        float acc = 0.f;
        #pragma unroll 8
        for (int k = 0; k < 64; ++k) acc += row[k] * W[k * 64 + col];
        if (part == 0) out[n * 64 + j] = acc;
        else out[N * 64 + n * 192 + (j - 64)] = acc;
        __syncthreads();
    }
}

// ---------------------------------------------------------------- fallback edge kernel
// (previous best: wave-per-edge with in-LDS weights + shfl matvecs)
__global__ __launch_bounds__(512, 1) void edge_k(
    const int* __restrict__ src, const int* __restrict__ dst,
    const float* __restrict__ r_ij, const float* __restrict__ z0g,
    const float* __restrict__ z1g, const float* __restrict__ emb,
    const float* __restrict__ Wenc, const float* __restrict__ benc,
    const float* __restrict__ Wsrc, const float* __restrict__ bsrc,
    const float* __restrict__ Wdst, const float* __restrict__ bdst,
    const float* __restrict__ Wgate, const float* __restrict__ bgate,
    const float* __restrict__ Ws, const float* __restrict__ Wv,
    float* __restrict__ out, int N, int E)
{
    __shared__ float sWsrc[4096];
    __shared__ float sWdst[4096];
    __shared__ float sWg[16384];
    __shared__ float sWs[4096];
    __shared__ float sWv[4096];
    __shared__ float sWe[512];
    __shared__ float sB[64];
    __shared__ float sBg[256];
    __shared__ int sFl[2];

    if (threadIdx.x == 0) {
        const u32* ps = (const u32*)src;
        const u32* pd = (const u32*)dst;
        int s64 = 1, d64 = 1;
        for (int i = 1; i < 128; i += 2) {
            if (ps[i] != 0u) s64 = 0;
            if (pd[i] != 0u) d64 = 0;
        }
        sFl[0] = s64;
        sFl[1] = d64;
    }
    for (int i = threadIdx.x; i < 4096; i += 512) {
        sWsrc[i] = Wsrc[i];
        sWdst[i] = Wdst[i];
        sWs[i] = Ws[i];
        sWv[i] = Wv[i];
    }
    for (int i = threadIdx.x; i < 16384; i += 512) sWg[i] = Wgate[i];
    for (int i = threadIdx.x; i < 512; i += 512) sWe[i] = Wenc[i];
    if (threadIdx.x < 64)
        sB[threadIdx.x] = benc[threadIdx.x] + bsrc[threadIdx.x] + bdst[threadIdx.x];
    if (threadIdx.x < 256) sBg[threadIdx.x] = bgate[threadIdx.x];
    __syncthreads();

    const int wid = threadIdx.x >> 6, lane = threadIdx.x & 63;
    const int i64s = sFl[0], i64d = sFl[1];

    for (int e = blockIdx.x * 8 + wid; e < E; e += gridDim.x * 8) {
        const int s = i64s ? src[2 * e] : src[e];
        const int t = i64d ? dst[2 * e] : dst[e];
        if (s < 0 || s >= N || t < 0 || t >= N) continue;

        const float es = emb[s * 64 + lane];
        const float et = emb[t * 64 + lane];
        float de = sB[lane];
        #pragma unroll 8
        for (int k = 0; k < 64; ++k) {
            de += __shfl(es, k, 64) * sWsrc[(k << 6) + lane];
            de += __shfl(et, k, 64) * sWdst[(k << 6) + lane];
        }
        const float r0 = r_ij[e * 3 + 0];
        const float r1 = r_ij[e * 3 + 1];
        const float r2 = r_ij[e * 3 + 2];
        const float d = sqrtf(r0 * r0 + r1 * r1 + r2 * r2);
        #pragma unroll
        for (int m = 0; m < 8; ++m) {
            const float mu = (2.0f / 7.0f) * (float)m;
            const float tt = (d - mu) * 4.0f;
            de += __expf(-tt * tt) * sWe[m * 64 + lane];
        }

        const float v0 = r0 * 3.5f, v1 = r1 * 3.5f, v2 = r2 * 3.5f;
        const float inv = rsqrtf(1.0f + v0 * v0 + v1 * v1 + v2 * v2);
        const float h0 = v0 * inv, h1 = v1 * inv, h2 = v2 * inv;

        const float z0v = z0g[t * 64 + lane];
        const float za = z1g[t * 192 + lane];
        const float zb = z1g[t * 192 + 64 + lane];
        const float zc = z1g[t * 192 + 128 + lane];
        const float uu = h0 * za + h1 * zb + h2 * zc;

        float g0 = sBg[lane], g1 = sBg[64 + lane], g2 = sBg[128 + lane], g3 = sBg[192 + lane];
        #pragma unroll 8
        for (int k = 0; k < 64; ++k) {
            const float dk = __shfl(de, k, 64);
            const float* w = &sWg[(k << 8) + lane];
            g0 += dk * w[0];
            g1 += dk * w[64];
            g2 += dk * w[128];
            g3 += dk * w[192];
        }

        const float smsg = g0 * z0v + g1 * uu;
        const float vm0 = g2 * za + g3 * h0 * z0v;
        const float vm1 = g2 * zb + g3 * h1 * z0v;
        const float vm2 = g2 * zc + g3 * h2 * z0v;

        float p0 = 0.f, q0 = 0.f, q1 = 0.f, q2 = 0.f;
        #pragma unroll 8
        for (int k = 0; k < 64; ++k) {
            const float sk = __shfl(smsg, k, 64);
            const float a = __shfl(vm0, k, 64);
            const float b = __shfl(vm1, k, 64);
            const float c = __shfl(vm2, k, 64);
            p0 += sk * sWs[(k << 6) + lane];
            const float wv = sWv[(k << 6) + lane];
            q0 += a * wv;
            q1 += b * wv;
            q2 += c * wv;
        }

        atomicAdd(&out[s * 64 + lane], p0);
        const int b1 = N * 64 + s * 192 + lane;
        atomicAdd(&out[b1], q0);
        atomicAdd(&out[b1 + 64], q1);
        atomicAdd(&out[b1 + 128], q2);
    }
}

extern "C" void kernel_launch(void* const* d_in, const int* in_sizes, int n_in,
                              void* d_out, int out_size, void* d_ws, size_t ws_size,
                              hipStream_t stream) {
    const int* src = (const int*)d_in[0];
    const int* dst = (const int*)d_in[1];
    const float* r_ij = (const float*)d_in[2];
    const float* z0g  = (const float*)d_in[3];
    const float* z1g  = (const float*)d_in[4];
    const float* emb  = (const float*)d_in[5];
    const float* Wenc = (const float*)d_in[6];
    const float* benc = (const float*)d_in[7];
    const float* Wsrc = (const float*)d_in[8];
    const float* bsrc = (const float*)d_in[9];
    const float* Wdst = (const float*)d_in[10];
    const float* bdst = (const float*)d_in[11];
    const float* Wgate = (const float*)d_in[12];
    const float* bgate = (const float*)d_in[13];
    const float* Ws = (const float*)d_in[14];
    const float* Wv = (const float*)d_in[15];

    const int N = out_size / 256;                    // out0 N*64 + out1 N*192
    int E = in_sizes[0];
    if (in_sizes[2] / 3 < E) E = in_sizes[2] / 3;    // robustness

    zero_k<<<2048, 256, 0, stream>>>((float*)d_out, out_size);

    float* ws = (float*)d_ws;
    const size_t need = ((size_t)WS_GS + 2u * (size_t)N * 256u) * sizeof(float);
    if (ws != nullptr && ws_size >= need) {
        compose_k<<<73, 256, 0, stream>>>(Wsrc, Wdst, Wenc, benc, bsrc, bdst,
                                          Wgate, bgate, ws);
        float* GS = ws + WS_GS;
        float* GD = GS + (size_t)N * 256;
        nodepre_k<<<512, 512, 0, stream>>>(emb, ws, GS, GD, N);
        edge_fast_k<<<2048, 256, 0, stream>>>(src, dst, r_ij, z0g, z1g, GS, GD,
                                              ws + WS_WEG, ws + WS_BALL,
                                              (float*)d_out, N, E);
        nodepost_k<<<2048, 256, 0, stream>>>((float*)d_out, Ws, Wv, N);
    } else {
        edge_k<<<2048, 512, 0, stream>>>(src, dst, r_ij, z0g, z1g, emb, Wenc, benc,
                                         Wsrc, bsrc, Wdst, bdst, Wgate, bgate, Ws, Wv,
                                         (float*)d_out, N, E);
    }
}